// Round 4
// baseline (4534.605 us; speedup 1.0000x reference)
//
#include <hip/hip_runtime.h>
#include <hip/hip_bf16.h>

typedef __hip_bfloat16 bf16;
typedef __attribute__((ext_vector_type(8))) short s16x8;   // 8 bf16 (MFMA A/B frag)
typedef __attribute__((ext_vector_type(4))) float f32x4;   // MFMA C/D frag
typedef __attribute__((ext_vector_type(4))) int   i32x4;

#define BATCH   64
#define SEQ     256
#define HID     1024
#define GATES   4096
#define NWG     256
#define THREADS 256
#define UNITS   8            // hidden units per WG
#define NCOLS   32           // gate columns per WG (4 gates x 8 units)
#define ROWSTRIDE 2056       // 2048 K + 8 pad elems (LDS bank de-alias)
#define GSTRIDE 33           // gates LDS row stride (+1 pad)
#define BH      (BATCH * HID)

#define H0_SLOTS 4           // h0 bf16 ring: used ONLY for t>=252 (each slot written once)
#define H1_SLOTS 2
#define FLAG_ELEMS ((size_t)6 * BH)            // flags start after h slots (bf16 elems)
#define WS_BYTES  (FLAG_ELEMS * 2 + 256 * 4)   // 786,432 + 1,024 per-WG epoch flags

#define OUT_HN  ((size_t)BATCH * SEQ * HID)
#define OUT_CN  (OUT_HN + 2ull * BATCH * HID)

// fp32 -> bf16 bits, round-to-nearest-even
__device__ __forceinline__ short f2bf(float f) {
    unsigned int u = __builtin_bit_cast(unsigned int, f);
    u = (u + 0x7fffu + ((u >> 16) & 1u)) >> 16;
    return (short)u;
}

// 8B agent-scope write-through store (payload must reach MALL for cross-XCD reads)
__device__ __forceinline__ void st8(void* p, float lo, float hi) {
    union { float f[2]; unsigned long long u; } v;
    v.f[0] = lo; v.f[1] = hi;
    __hip_atomic_store((unsigned long long*)p, v.u, __ATOMIC_RELAXED, __HIP_MEMORY_SCOPE_AGENT);
}

// fp32-input GEMM slice over K=1024 with PLAIN CACHED loads (L1+L2). Used for
// h0 payload rows in `out` (write-once addresses -> no staleness, no fences)
// and for the embedding rows. Identical numerics to the bf16 path (same f2bf).
__device__ __forceinline__ void gemm_f32c(const float* xrow, const bf16* s0, const bf16* s1,
                                          f32x4& a0, f32x4& a1)
{
#pragma unroll
    for (int c = 0; c < 4; ++c) {
        f32x4 xv[16];
#pragma unroll
        for (int i = 0; i < 8; ++i) {
            const float* p = xrow + (c * 8 + i) * 32;
            xv[2 * i]     = *(const f32x4*)p;
            xv[2 * i + 1] = *(const f32x4*)(p + 4);
        }
#pragma unroll
        for (int i = 0; i < 8; ++i) {
            const int kk = c * 8 + i;
            s16x8 af;
#pragma unroll
            for (int j = 0; j < 4; ++j) {
                af[j]     = f2bf(xv[2 * i][j]);
                af[4 + j] = f2bf(xv[2 * i + 1][j]);
            }
            s16x8 b0 = *(const s16x8*)(s0 + kk * 32);
            s16x8 b1 = *(const s16x8*)(s1 + kk * 32);
            a0 = __builtin_amdgcn_mfma_f32_16x16x32_bf16(af, b0, a0, 0, 0, 0);
            a1 = __builtin_amdgcn_mfma_f32_16x16x32_bf16(af, b1, a1, 0, 0, 0);
        }
    }
}

// bf16 GEMM slice, loads at device coherent point (sc0 sc1 bypass): used for the
// h1 ring (2-slot reuse forbids caching) and the h0 ring tail (t>=252).
// Single base + immediate offsets, counted-vmcnt pipeline, sched_barrier (rule #18).
#define MM8(B0) \
    _Pragma("unroll") \
    for (int kk = (B0); kk < (B0) + 8; ++kk) { \
        s16x8 b0 = *(const s16x8*)(s0 + kk * 32); \
        s16x8 b1 = *(const s16x8*)(s1 + kk * 32); \
        s16x8 av = __builtin_bit_cast(s16x8, h[kk]); \
        a0 = __builtin_amdgcn_mfma_f32_16x16x32_bf16(av, b0, a0, 0, 0, 0); \
        a1 = __builtin_amdgcn_mfma_f32_16x16x32_bf16(av, b1, a1, 0, 0, 0); \
    }

__device__ __forceinline__ void gemm_bt(const bf16* xrow, const bf16* s0, const bf16* s1,
                                        f32x4& a0, f32x4& a1)
{
    i32x4 h[32];
#define LD(i, OFF) asm volatile("global_load_dwordx4 %0, %1, off offset:" OFF " sc0 sc1" \
                                : "=v"(h[i]) : "v"(xrow))
    LD(0, "0");    LD(1, "64");   LD(2, "128");  LD(3, "192");
    LD(4, "256");  LD(5, "320");  LD(6, "384");  LD(7, "448");
    LD(8, "512");  LD(9, "576");  LD(10, "640"); LD(11, "704");
    LD(12, "768"); LD(13, "832"); LD(14, "896"); LD(15, "960");
    LD(16, "1024"); LD(17, "1088"); LD(18, "1152"); LD(19, "1216");
    LD(20, "1280"); LD(21, "1344"); LD(22, "1408"); LD(23, "1472");
    asm volatile("s_waitcnt vmcnt(16)"); __builtin_amdgcn_sched_barrier(0);
    MM8(0)
    LD(24, "1536"); LD(25, "1600"); LD(26, "1664"); LD(27, "1728");
    LD(28, "1792"); LD(29, "1856"); LD(30, "1920"); LD(31, "1984");
    asm volatile("s_waitcnt vmcnt(16)"); __builtin_amdgcn_sched_barrier(0);
    MM8(8)
    asm volatile("s_waitcnt vmcnt(8)");  __builtin_amdgcn_sched_barrier(0);
    MM8(16)
    asm volatile("s_waitcnt vmcnt(0)");  __builtin_amdgcn_sched_barrier(0);
    MM8(24)
#undef LD
}

// Per-wave poll: lane l watches flags[l], flags[64+l] of a layer's 128 epochs.
__device__ __forceinline__ void wave_poll(unsigned int* f, int tgt) {
    if (tgt <= 0) return;
    const int l = threadIdx.x & 63;
    unsigned int* p0 = f + l;
    unsigned int* p1 = f + 64 + l;
    for (;;) {
        int a = (int)__hip_atomic_load(p0, __ATOMIC_RELAXED, __HIP_MEMORY_SCOPE_AGENT);
        int b = (int)__hip_atomic_load(p1, __ATOMIC_RELAXED, __HIP_MEMORY_SCOPE_AGENT);
        if (__all((a >= tgt) && (b >= tgt))) break;
        __builtin_amdgcn_s_sleep(1);
    }
    asm volatile("" ::: "memory");
}

__global__ void ws_init(unsigned int* p, int n) {
    for (int i = blockIdx.x * blockDim.x + threadIdx.x; i < n; i += gridDim.x * blockDim.x)
        p[i] = 0u;
}

__global__ void __launch_bounds__(THREADS, 1)
lstm_enc(const int* __restrict__ src, const float* __restrict__ Wemb,
         const float* __restrict__ Wih, const float* __restrict__ Whh,
         const float* __restrict__ bih, const float* __restrict__ bhh,
         float* __restrict__ out, bf16* __restrict__ hbuf)
{
    __shared__ __align__(16) bf16 slab[NCOLS][ROWSTRIDE];   // 131,584 B (persists)
    __shared__ float gates[BATCH][GSTRIDE];                 // 8,448 B
    __shared__ float bias[NCOLS];

    const int wg    = blockIdx.x;
    const int layer = wg >> 7;                 // 0-127: layer0, 128-255: layer1
    const int wgl   = wg & 127;
    const int j0    = wgl * UNITS;
    const int tid   = threadIdx.x;
    const int lane  = tid & 63;
    const int wave  = tid >> 6;
    const int m     = lane & 15;
    const int kq    = (lane >> 4) * 8;
    const int b_a   = wave * 16 + m;           // batch row this lane loads for A

    // ---- weight slab: rows = [i8|f8|g8|o8], K = [W_ih row | W_hh row], fp32->bf16 ----
    for (int r = 0; r < NCOLS; ++r) {
        int g = r >> 3, u = r & 7;
        size_t grow = (size_t)layer * GATES * HID + (size_t)(g * HID + j0 + u) * HID;
        int k = tid * 8;                       // 256 threads x 8 = 2048 exact
        const float* s = (k < HID) ? (Wih + grow + k) : (Whh + grow + (k - HID));
        s16x8 v;
#pragma unroll
        for (int j = 0; j < 8; ++j) v[j] = f2bf(s[j]);
        *(s16x8*)&slab[r][k] = v;
    }
    if (tid < NCOLS) {
        int g = tid >> 3, u = tid & 7;
        int off = layer * GATES + g * HID + j0 + u;
        bias[tid] = bih[off] + bhh[off];
    }
    __syncthreads();

    bf16* h0 = hbuf;                           // [4][B][H] tail ring (t>=252 only)
    bf16* h1 = hbuf + H0_SLOTS * BH;           // [2][B][H] ring
    unsigned int* flags = (unsigned int*)(hbuf + FLAG_ELEMS);  // per-WG epoch counters
    unsigned int* f0 = flags;                  // layer0 epochs [0..127]
    unsigned int* f1 = flags + 128;            // layer1 epochs [0..127]

    // epilogue mapping: thread -> (bb = tid>>2, u0 = 2*(tid&3)); c-state in registers
    const int bb = tid >> 2;
    const int u0 = (tid & 3) * 2;
    float c_lo = 0.f, c_hi = 0.f;

    int sv = (layer == 0) ? src[b_a * SEQ] : 0;   // prefetched src token

    for (int t = 0; t < SEQ; ++t) {
        f32x4 acc0 = {0.f, 0.f, 0.f, 0.f};
        f32x4 acc1 = {0.f, 0.f, 0.f, 0.f};

        if (layer == 0) {
            // ---- x @ W_ih^T from embedding (cached fp32): no cross-WG dep ----
            const float* xF = Wemb + (size_t)sv * HID + kq;
            if (t + 1 < SEQ) sv = src[b_a * SEQ + t + 1];
            gemm_f32c(xF, &slab[m][kq], &slab[16 + m][kq], acc0, acc1);
            // own layer done t-1 -> h0[t-1] readable. NO ring-protect: L0 free-runs
            // (payload rows are write-once; tail ring slots written exactly once).
            wave_poll(f0, t);
            if (t >= 1) {
                if (t <= 252)   // h0[t-1] payload lives in out row (t-1)+4 = t+3
                    gemm_f32c(out + ((size_t)b_a * SEQ + (t + 3)) * HID + kq,
                              &slab[m][HID + kq], &slab[16 + m][HID + kq], acc0, acc1);
                else            // tail: bf16 ring slot (t-1)&3, bypass loads
                    gemm_bt(h0 + (size_t)((t - 1) & 3) * BH + b_a * HID + kq,
                            &slab[m][HID + kq], &slab[16 + m][HID + kq], acc0, acc1);
            }
        } else {
            // L0 runs ahead -> usually pre-satisfied
            wave_poll(f0, t + 1);
            if (t <= 251)       // x = h0[t] payload in out row t+4 (cached, L2-multicast)
                gemm_f32c(out + ((size_t)b_a * SEQ + (t + 4)) * HID + kq,
                          &slab[m][kq], &slab[16 + m][kq], acc0, acc1);
            else                // tail: bf16 ring slot t&3
                gemm_bt(h0 + (size_t)(t & 3) * BH + b_a * HID + kq,
                        &slab[m][kq], &slab[16 + m][kq], acc0, acc1);
            // own layer done t-1 -> h1[t-1] readable
            wave_poll(f1, t);
            if (t >= 1)
                gemm_bt(h1 + (size_t)((t - 1) & 1) * BH + b_a * HID + kq,
                        &slab[m][HID + kq], &slab[16 + m][HID + kq], acc0, acc1);
        }

        // C/D layout: col = lane&15, row = (lane>>4)*4 + r  (verified m89/m91)
        const int rowg = wave * 16 + (lane >> 4) * 4;
#pragma unroll
        for (int r = 0; r < 4; ++r) {
            gates[rowg + r][m]      = acc0[r];
            gates[rowg + r][16 + m] = acc1[r];
        }
        __syncthreads();   // #1: gates complete

        // ---- epilogue: 2 adjacent units per thread, c-state in registers ----
        float gi0 = gates[bb][u0]      + bias[u0];
        float gi1 = gates[bb][u0 + 1]  + bias[u0 + 1];
        float gf0 = gates[bb][u0 + 8]  + bias[u0 + 8];
        float gf1 = gates[bb][u0 + 9]  + bias[u0 + 9];
        float gg0 = gates[bb][u0 + 16] + bias[u0 + 16];
        float gg1 = gates[bb][u0 + 17] + bias[u0 + 17];
        float go0 = gates[bb][u0 + 24] + bias[u0 + 24];
        float go1 = gates[bb][u0 + 25] + bias[u0 + 25];
        float si0 = 1.f / (1.f + __expf(-gi0)), si1 = 1.f / (1.f + __expf(-gi1));
        float sf0 = 1.f / (1.f + __expf(-gf0)), sf1 = 1.f / (1.f + __expf(-gf1));
        float so0 = 1.f / (1.f + __expf(-go0)), so1 = 1.f / (1.f + __expf(-go1));
        float tg0 = tanhf(gg0), tg1 = tanhf(gg1);
        c_lo = sf0 * c_lo + si0 * tg0;
        c_hi = sf1 * c_hi + si1 * tg1;
        float h_lo = so0 * tanhf(c_lo);
        float h_hi = so1 * tanhf(c_hi);

        if (layer == 0) {
            if (t <= 251)   // payload: fp32 write-through into out row t+4
                st8(out + ((size_t)bb * SEQ + (t + 4)) * HID + j0 + u0, h_lo, h_hi);
            else {          // tail ring: bf16, write-through
                unsigned int hp = (unsigned int)(unsigned short)f2bf(h_lo) |
                                  ((unsigned int)(unsigned short)f2bf(h_hi) << 16);
                __hip_atomic_store((unsigned int*)(h0 + (size_t)(t & 3) * BH + bb * HID + j0 + u0),
                                   hp, __ATOMIC_RELAXED, __HIP_MEMORY_SCOPE_AGENT);
            }
        } else {            // h1 ring: bf16, write-through
            unsigned int hp = (unsigned int)(unsigned short)f2bf(h_lo) |
                              ((unsigned int)(unsigned short)f2bf(h_hi) << 16);
            __hip_atomic_store((unsigned int*)(h1 + (size_t)(t & 1) * BH + bb * HID + j0 + u0),
                               hp, __ATOMIC_RELAXED, __HIP_MEMORY_SCOPE_AGENT);
        }

        __syncthreads();   // #2: drains vmcnt(0) -> payload/ring stores at MALL
        asm volatile("" ::: "memory");
        if (tid == 0)      // per-WG epoch store
            __hip_atomic_store(flags + wg, (unsigned int)(t + 1),
                               __ATOMIC_RELAXED, __HIP_MEMORY_SCOPE_AGENT);

        // ---- post-flag final outputs (no in-kernel readers; safe to overwrite
        //      payload rows: all payload reads are flag-ordered before this) ----
        if (layer == 1)
            *(float2*)(out + ((size_t)bb * SEQ + t) * HID + j0 + u0) = make_float2(h_lo, h_hi);
        if (t == SEQ - 1) {
            size_t o = ((size_t)layer * BATCH + bb) * HID + j0 + u0;
            *(float2*)(out + OUT_HN + o) = make_float2(h_lo, h_hi);
            *(float2*)(out + OUT_CN + o) = make_float2(c_lo, c_hi);
        }
    }
}

extern "C" void kernel_launch(void* const* d_in, const int* in_sizes, int n_in,
                              void* d_out, int out_size, void* d_ws, size_t ws_size,
                              hipStream_t stream) {
    const int*   src  = (const int*)d_in[0];
    const float* emb  = (const float*)d_in[1];
    const float* W_ih = (const float*)d_in[2];
    const float* W_hh = (const float*)d_in[3];
    const float* b_ih = (const float*)d_in[4];
    const float* b_hh = (const float*)d_in[5];
    float* out  = (float*)d_out;
    bf16*  hbuf = (bf16*)d_ws;                 // uses 787,456 B

    // zero rings + flag words (ws is re-poisoned 0xAA before every replay)
    unsigned int* wsp = (unsigned int*)d_ws;
    int n = (int)(WS_BYTES / 4);
    ws_init<<<256, 256, 0, stream>>>(wsp, n);

    void* args[] = {&src, &emb, &W_ih, &W_hh, &b_ih, &b_hh, &out, &hbuf};
    hipLaunchCooperativeKernel((void*)lstm_enc, dim3(NWG), dim3(THREADS),
                               args, 0, stream);
}

// Round 5
// 3769.699 us; speedup vs baseline: 1.2029x; 1.2029x over previous
//
#include <hip/hip_runtime.h>
#include <hip/hip_bf16.h>

typedef __hip_bfloat16 bf16;
typedef __attribute__((ext_vector_type(8))) short s16x8;   // 8 bf16 (MFMA A/B frag)
typedef __attribute__((ext_vector_type(4))) float f32x4;   // MFMA C/D frag
typedef __attribute__((ext_vector_type(4))) int   i32x4;

#define BATCH   64
#define SEQ     256
#define HID     1024
#define GATES   4096
#define NWG     256
#define THREADS 256
#define UNITS   8            // hidden units per WG
#define NCOLS   32           // gate columns per WG (4 gates x 8 units)
#define ROWSTRIDE 2056       // 2048 K + 8 pad elems (LDS bank de-alias)
#define GSTRIDE 33           // gates LDS row stride (+1 pad)
#define BH      (BATCH * HID)

#define H0_SLOTS 4           // layer0 h ring (lets layer0 run ahead)
#define H1_SLOTS 2
#define FLAG_ELEMS ((size_t)6 * BH)            // flags start after h slots (bf16 elems)
#define WS_BYTES  (FLAG_ELEMS * 2 + 256 * 4)   // 786,432 + 1,024 per-WG epoch flags

#define OUT_HN  ((size_t)BATCH * SEQ * HID)
#define OUT_CN  (OUT_HN + 2ull * BATCH * HID)

// fp32 -> bf16 bits, round-to-nearest-even
__device__ __forceinline__ short f2bf(float f) {
    unsigned int u = __builtin_bit_cast(unsigned int, f);
    u = (u + 0x7fffu + ((u >> 16) & 1u)) >> 16;
    return (short)u;
}

// Embedding x-GEMM: plain cached fp32 loads (rows re-read across WGs share via
// L2/MALL normally; overlaps the flag polls).
__device__ __forceinline__ void gemm_f32c(const float* xrow, const bf16* s0, const bf16* s1,
                                          f32x4& a0, f32x4& a1)
{
#pragma unroll
    for (int c = 0; c < 4; ++c) {
        f32x4 xv[16];
#pragma unroll
        for (int i = 0; i < 8; ++i) {
            const float* p = xrow + (c * 8 + i) * 32;
            xv[2 * i]     = *(const f32x4*)p;
            xv[2 * i + 1] = *(const f32x4*)(p + 4);
        }
#pragma unroll
        for (int i = 0; i < 8; ++i) {
            const int kk = c * 8 + i;
            s16x8 af;
#pragma unroll
            for (int j = 0; j < 4; ++j) {
                af[j]     = f2bf(xv[2 * i][j]);
                af[4 + j] = f2bf(xv[2 * i + 1][j]);
            }
            s16x8 b0 = *(const s16x8*)(s0 + kk * 32);
            s16x8 b1 = *(const s16x8*)(s1 + kk * 32);
            a0 = __builtin_amdgcn_mfma_f32_16x16x32_bf16(af, b0, a0, 0, 0, 0);
            a1 = __builtin_amdgcn_mfma_f32_16x16x32_bf16(af, b1, a1, 0, 0, 0);
        }
    }
}

// K-STAGGERED bf16 GEMM over K=1024, coherent-point loads (sc0 sc1).
// 8 chunks of 128 elements (256 B), visited in WG-rotated order: breaks the
// byte-identical address-stream clustering of 128 WGs at the MALL banks.
// h-register map, slab reads and MFMA order rotate together (fp32 accumulate
// is reorder-tolerant). Counted-vmcnt pipeline + sched_barrier (rule #18).
__device__ __forceinline__ void gemm_stag(const bf16* xrow, const bf16* s0, const bf16* s1,
                                          int rot, f32x4& a0, f32x4& a1)
{
    const bf16* xb[8]; const bf16* c0[8]; const bf16* c1[8];
#pragma unroll
    for (int j = 0; j < 8; ++j) {
        const int cb = ((j + rot) & 7) * 128;    // element offset of chunk j
        xb[j] = xrow + cb; c0[j] = s0 + cb; c1[j] = s1 + cb;
    }
    i32x4 h[32];
#define LD4(j) \
    asm volatile("global_load_dwordx4 %0, %1, off sc0 sc1"            : "=v"(h[4*(j)+0]) : "v"(xb[j])); \
    asm volatile("global_load_dwordx4 %0, %1, off offset:64 sc0 sc1"  : "=v"(h[4*(j)+1]) : "v"(xb[j])); \
    asm volatile("global_load_dwordx4 %0, %1, off offset:128 sc0 sc1" : "=v"(h[4*(j)+2]) : "v"(xb[j])); \
    asm volatile("global_load_dwordx4 %0, %1, off offset:192 sc0 sc1" : "=v"(h[4*(j)+3]) : "v"(xb[j]));
#define MM4(j) \
    _Pragma("unroll") \
    for (int i = 0; i < 4; ++i) { \
        s16x8 b0 = *(const s16x8*)(c0[j] + i * 32); \
        s16x8 b1 = *(const s16x8*)(c1[j] + i * 32); \
        s16x8 av = __builtin_bit_cast(s16x8, h[4*(j)+i]); \
        a0 = __builtin_amdgcn_mfma_f32_16x16x32_bf16(av, b0, a0, 0, 0, 0); \
        a1 = __builtin_amdgcn_mfma_f32_16x16x32_bf16(av, b1, a1, 0, 0, 0); \
    }
    LD4(0) LD4(1) LD4(2) LD4(3) LD4(4) LD4(5)
    asm volatile("s_waitcnt vmcnt(16)"); __builtin_amdgcn_sched_barrier(0);
    MM4(0) MM4(1)
    LD4(6) LD4(7)
    asm volatile("s_waitcnt vmcnt(16)"); __builtin_amdgcn_sched_barrier(0);
    MM4(2) MM4(3)
    asm volatile("s_waitcnt vmcnt(8)");  __builtin_amdgcn_sched_barrier(0);
    MM4(4) MM4(5)
    asm volatile("s_waitcnt vmcnt(0)");  __builtin_amdgcn_sched_barrier(0);
    MM4(6) MM4(7)
#undef LD4
#undef MM4
}

// Per-wave poll: lane l watches flags[l], flags[64+l] of a layer's 128 epochs.
__device__ __forceinline__ void wave_poll(unsigned int* f, int tgt) {
    if (tgt <= 0) return;
    const int l = threadIdx.x & 63;
    unsigned int* p0 = f + l;
    unsigned int* p1 = f + 64 + l;
    for (;;) {
        int a = (int)__hip_atomic_load(p0, __ATOMIC_RELAXED, __HIP_MEMORY_SCOPE_AGENT);
        int b = (int)__hip_atomic_load(p1, __ATOMIC_RELAXED, __HIP_MEMORY_SCOPE_AGENT);
        if (__all((a >= tgt) && (b >= tgt))) break;
        __builtin_amdgcn_s_sleep(1);
    }
    asm volatile("" ::: "memory");
}

__global__ void ws_init(unsigned int* p, int n) {
    for (int i = blockIdx.x * blockDim.x + threadIdx.x; i < n; i += gridDim.x * blockDim.x)
        p[i] = 0u;
}

__global__ void __launch_bounds__(THREADS, 1)
lstm_enc(const int* __restrict__ src, const float* __restrict__ Wemb,
         const float* __restrict__ Wih, const float* __restrict__ Whh,
         const float* __restrict__ bih, const float* __restrict__ bhh,
         float* __restrict__ out, bf16* __restrict__ hbuf)
{
    __shared__ __align__(16) bf16 slab[NCOLS][ROWSTRIDE];   // 131,584 B (persists)
    __shared__ float gates[BATCH][GSTRIDE];                 // 8,448 B
    __shared__ float bias[NCOLS];

    const int wg    = blockIdx.x;
    const int layer = wg >> 7;                 // 0-127: layer0, 128-255: layer1
    const int wgl   = wg & 127;
    const int j0    = wgl * UNITS;
    const int tid   = threadIdx.x;
    const int lane  = tid & 63;
    const int wave  = tid >> 6;
    const int m     = lane & 15;
    const int kq    = (lane >> 4) * 8;
    const int b_a   = wave * 16 + m;           // batch row this lane loads for A
    const int rot   = wg & 7;                  // K-stagger class (MALL de-cluster)

    // ---- weight slab: rows = [i8|f8|g8|o8], K = [W_ih row | W_hh row], fp32->bf16 ----
    for (int r = 0; r < NCOLS; ++r) {
        int g = r >> 3, u = r & 7;
        size_t grow = (size_t)layer * GATES * HID + (size_t)(g * HID + j0 + u) * HID;
        int k = tid * 8;                       // 256 threads x 8 = 2048 exact
        const float* s = (k < HID) ? (Wih + grow + k) : (Whh + grow + (k - HID));
        s16x8 v;
#pragma unroll
        for (int j = 0; j < 8; ++j) v[j] = f2bf(s[j]);
        *(s16x8*)&slab[r][k] = v;
    }
    if (tid < NCOLS) {
        int g = tid >> 3, u = tid & 7;
        int off = layer * GATES + g * HID + j0 + u;
        bias[tid] = bih[off] + bhh[off];
    }
    __syncthreads();

    bf16* h0 = hbuf;                           // [4][B][H] ring
    bf16* h1 = hbuf + H0_SLOTS * BH;           // [2][B][H] ring
    unsigned int* flags = (unsigned int*)(hbuf + FLAG_ELEMS);  // per-WG epoch counters
    unsigned int* f0 = flags;                  // layer0 epochs [0..127]
    unsigned int* f1 = flags + 128;            // layer1 epochs [0..127]

    // epilogue mapping: thread -> (bb = tid>>2, u0 = 2*(tid&3)); c-state in registers
    const int bb = tid >> 2;
    const int u0 = (tid & 3) * 2;
    float c_lo = 0.f, c_hi = 0.f;

    int sv = (layer == 0) ? src[b_a * SEQ] : 0;   // prefetched src token

    for (int t = 0; t < SEQ; ++t) {
        f32x4 acc0 = {0.f, 0.f, 0.f, 0.f};
        f32x4 acc1 = {0.f, 0.f, 0.f, 0.f};

        if (layer == 0) {
            // ---- x @ W_ih^T from embedding (cached fp32): no cross-WG dep ----
            const float* xF = Wemb + (size_t)sv * HID + kq;
            if (t + 1 < SEQ) sv = src[b_a * SEQ + t + 1];
            gemm_f32c(xF, &slab[m][kq], &slab[16 + m][kq], acc0, acc1);
            // own layer done t-1 -> h0[t-1] readable
            wave_poll(f0, t);
            if (t >= 1)
                gemm_stag(h0 + (size_t)((t - 1) & (H0_SLOTS - 1)) * BH + b_a * HID + kq,
                          &slab[m][HID + kq], &slab[16 + m][HID + kq], rot, acc0, acc1);
            // ring protect: L1 done t-4 before we overwrite h0 slot t&3 (off the
            // recurrence path: h-GEMM above reads slot (t-1)&3, untouched by this)
            wave_poll(f1, t - 3);
        } else {
            // L0 runs ahead -> usually pre-satisfied
            wave_poll(f0, t + 1);
            gemm_stag(h0 + (size_t)(t & (H0_SLOTS - 1)) * BH + b_a * HID + kq,
                      &slab[m][kq], &slab[16 + m][kq], rot, acc0, acc1);
            // own layer done t-1 -> h1[t-1] readable (also ring-protects slot t&1)
            wave_poll(f1, t);
            if (t >= 1)
                gemm_stag(h1 + (size_t)((t - 1) & (H1_SLOTS - 1)) * BH + b_a * HID + kq,
                          &slab[m][HID + kq], &slab[16 + m][HID + kq], rot, acc0, acc1);
        }

        // C/D layout: col = lane&15, row = (lane>>4)*4 + r  (verified m89/m91)
        const int rowg = wave * 16 + (lane >> 4) * 4;
#pragma unroll
        for (int r = 0; r < 4; ++r) {
            gates[rowg + r][m]      = acc0[r];
            gates[rowg + r][16 + m] = acc1[r];
        }
        __syncthreads();   // #1: gates complete

        // ---- epilogue: 2 adjacent units per thread, c-state in registers ----
        float gi0 = gates[bb][u0]      + bias[u0];
        float gi1 = gates[bb][u0 + 1]  + bias[u0 + 1];
        float gf0 = gates[bb][u0 + 8]  + bias[u0 + 8];
        float gf1 = gates[bb][u0 + 9]  + bias[u0 + 9];
        float gg0 = gates[bb][u0 + 16] + bias[u0 + 16];
        float gg1 = gates[bb][u0 + 17] + bias[u0 + 17];
        float go0 = gates[bb][u0 + 24] + bias[u0 + 24];
        float go1 = gates[bb][u0 + 25] + bias[u0 + 25];
        float si0 = 1.f / (1.f + __expf(-gi0)), si1 = 1.f / (1.f + __expf(-gi1));
        float sf0 = 1.f / (1.f + __expf(-gf0)), sf1 = 1.f / (1.f + __expf(-gf1));
        float so0 = 1.f / (1.f + __expf(-go0)), so1 = 1.f / (1.f + __expf(-go1));
        float tg0 = tanhf(gg0), tg1 = tanhf(gg1);
        c_lo = sf0 * c_lo + si0 * tg0;
        c_hi = sf1 * c_hi + si1 * tg1;
        float h_lo = so0 * tanhf(c_lo);
        float h_hi = so1 * tanhf(c_hi);

        bf16* hw = ((layer == 0) ? h0 + (size_t)(t & (H0_SLOTS - 1)) * BH
                                 : h1 + (size_t)(t & (H1_SLOTS - 1)) * BH);
        unsigned int hp = (unsigned int)(unsigned short)f2bf(h_lo) |
                          ((unsigned int)(unsigned short)f2bf(h_hi) << 16);
        __hip_atomic_store((unsigned int*)(hw + bb * HID + j0 + u0), hp,
                           __ATOMIC_RELAXED, __HIP_MEMORY_SCOPE_AGENT);

        __syncthreads();   // #2: drains vmcnt(0) -> h stores at coherent point
        asm volatile("" ::: "memory");
        if (tid == 0)      // per-WG epoch store
            __hip_atomic_store(flags + wg, (unsigned int)(t + 1),
                               __ATOMIC_RELAXED, __HIP_MEMORY_SCOPE_AGENT);

        // ---- post-flag final outputs: off the recurrence critical path ----
        if (layer == 1)
            *(float2*)(out + ((size_t)bb * SEQ + t) * HID + j0 + u0) = make_float2(h_lo, h_hi);
        if (t == SEQ - 1) {
            size_t o = ((size_t)layer * BATCH + bb) * HID + j0 + u0;
            *(float2*)(out + OUT_HN + o) = make_float2(h_lo, h_hi);
            *(float2*)(out + OUT_CN + o) = make_float2(c_lo, c_hi);
        }
    }
}

extern "C" void kernel_launch(void* const* d_in, const int* in_sizes, int n_in,
                              void* d_out, int out_size, void* d_ws, size_t ws_size,
                              hipStream_t stream) {
    const int*   src  = (const int*)d_in[0];
    const float* emb  = (const float*)d_in[1];
    const float* W_ih = (const float*)d_in[2];
    const float* W_hh = (const float*)d_in[3];
    const float* b_ih = (const float*)d_in[4];
    const float* b_hh = (const float*)d_in[5];
    float* out  = (float*)d_out;
    bf16*  hbuf = (bf16*)d_ws;                 // uses 787,456 B

    // zero rings + flag words (ws is re-poisoned 0xAA before every replay)
    unsigned int* wsp = (unsigned int*)d_ws;
    int n = (int)(WS_BYTES / 4);
    ws_init<<<256, 256, 0, stream>>>(wsp, n);

    void* args[] = {&src, &emb, &W_ih, &W_hh, &b_ih, &b_hh, &out, &hbuf};
    hipLaunchCooperativeKernel((void*)lstm_enc, dim3(NWG), dim3(THREADS),
                               args, 0, stream);
}